// Round 5
// baseline (395.156 us; speedup 1.0000x reference)
//
#include <hip/hip_runtime.h>

typedef __attribute__((ext_vector_type(8))) short short8;
typedef __attribute__((ext_vector_type(8))) unsigned short ushort8;
typedef __attribute__((ext_vector_type(4))) float f32x4;
typedef __attribute__((ext_vector_type(2))) unsigned int uint2v;

// workspace float offsets
#define OFF_WC 0        // 1160*3
#define OFF_BC 3480     // 1160
#define OFF_W3 4640     // 640*12  folded conv*proj weights
#define OFF_TB 12320    // 640*4   per-tap bias (causal pad masking)
#define OFF_NW 14880    // 512     norm_w * colsum(out_proj_w)
#define OFF_Y_BYTES 262144   // bf16 Y buffer after this byte offset

__device__ __forceinline__ unsigned short f2bf(float f){
  unsigned int u = __float_as_uint(f);
  u = (u + 0x7FFFu + ((u >> 16) & 1u)) >> 16;
  return (unsigned short)u;
}
__device__ __forceinline__ float bf2f(unsigned short h){
  return __uint_as_float(((unsigned int)h) << 16);
}
__device__ __forceinline__ unsigned int cvtpk(float lo, float hi){
  unsigned int r;
  asm("v_cvt_pk_bf16_f32 %0, %1, %2" : "=v"(r) : "v"(lo), "v"(hi));
  return r;
}
__device__ __forceinline__ float softplusf_(float x){
  return (x > 15.f) ? x : log1pf(__expf(x));
}
__device__ __forceinline__ float siluf_(float x){
  return x * __fdividef(1.f, 1.f + __expf(-x));
}

// swizzled index into a [64][64] ushort tile
#define SW(row_, col_) ((row_)*64 + ((col_) ^ (((row_)&7)<<3)))

// ---- prep 1: Wc = in_proj_w @ W_in (1160x3), biasc = in_proj_w @ b_in ----
__global__ void prep1_kernel(const float* __restrict__ ipw,
                             const float* __restrict__ W_in,
                             const float* __restrict__ b_in,
                             float* __restrict__ wsf){
  int gw = (blockIdx.x*256 + threadIdx.x) >> 6;   // wave per row
  int lane = threadIdx.x & 63;
  if (gw >= 1160) return;
  const float* row = ipw + (size_t)gw*256;
  float a0=0.f,a1=0.f,a2=0.f,ab=0.f;
  #pragma unroll
  for (int m = lane; m < 256; m += 64){
    float w = row[m];
    a0 = fmaf(w, W_in[m*3+0], a0);
    a1 = fmaf(w, W_in[m*3+1], a1);
    a2 = fmaf(w, W_in[m*3+2], a2);
    ab = fmaf(w, b_in[m], ab);
  }
  #pragma unroll
  for (int o=32;o;o>>=1){
    a0 += __shfl_xor(a0,o); a1 += __shfl_xor(a1,o);
    a2 += __shfl_xor(a2,o); ab += __shfl_xor(ab,o);
  }
  if (lane==0){
    wsf[OFF_WC + gw*3+0]=a0; wsf[OFF_WC + gw*3+1]=a1; wsf[OFF_WC + gw*3+2]=a2;
    wsf[OFF_BC + gw]=ab;
  }
}

// ---- prep 2: folded conv tables + nw = norm_w * colsum(out_proj_w) ----
__global__ void prep2_kernel(const float* __restrict__ conv_w,
                             const float* __restrict__ norm_w,
                             const float* __restrict__ out_proj_w,
                             float* __restrict__ wsf){
  int r = blockIdx.x*256 + threadIdx.x;
  if (r < 640){
    float bc = wsf[OFF_BC + 512 + r];
    #pragma unroll
    for (int i=0;i<4;i++){
      float cw = conv_w[r*4+i];
      wsf[OFF_TB + r*4+i] = cw*bc;
      wsf[OFF_W3 + r*12 + i*3+0] = cw * wsf[OFF_WC + (512+r)*3+0];
      wsf[OFF_W3 + r*12 + i*3+1] = cw * wsf[OFF_WC + (512+r)*3+1];
      wsf[OFF_W3 + r*12 + i*3+2] = cw * wsf[OFF_WC + (512+r)*3+2];
    }
  }
  if (r < 512){
    float s=0.f;
    for (int m=0;m<256;m++) s += out_proj_w[(size_t)m*512 + r];
    wsf[OFF_NW + r] = norm_w[r]*s;
  }
}

// ---- SSD: one block per (b,h); state in regs across the 64-chunk loop ----
// Schedule: R1 = STAGE(c+1) | barrier | R2 = E(c) + D(c+1) (dbuf Mm/Sb) | barrier
__global__ __launch_bounds__(1024, 4) void ssd_kernel(
    const float* __restrict__ obs, const float* __restrict__ conv_b,
    const float* __restrict__ dt_bias, const float* __restrict__ A_log,
    const float* __restrict__ D_param, const float* __restrict__ wsf,
    unsigned short* __restrict__ Yg)
{
  __shared__ __align__(16) unsigned short BsT[2][4096];   // B   [t][n]
  __shared__ __align__(16) unsigned short CsT[2][4096];   // C   [t][n]
  __shared__ __align__(16) unsigned short XDTt[2][4096];  // x*dt [p][t]
  __shared__ __align__(16) unsigned short BDTt[2][4096];  // B*dcy [n][t]
  __shared__ __align__(16) unsigned short MmD[2][4096];   // M [l][s] dbuf (W3T alias in prologue)
  __shared__ __align__(16) unsigned short SbD[2][4096];   // S [p][n] dbuf
  __shared__ __align__(16) unsigned short OW[2][64*40];   // obs window (K pad 12->40)
  __shared__ __align__(16) float acs_l[4096];
  __shared__ __align__(16) float dt_l[4096];
  __shared__ float CBe[192];

  const int tid  = threadIdx.x;
  const int b    = blockIdx.x >> 3;
  const int h    = blockIdx.x & 7;
  const int lane = tid & 63;
  const int wid  = tid >> 6;          // 0..15
  const int ln15 = lane & 15;
  const int quad = (lane >> 4) & 3;
  const int quad4 = quad*4, quad8 = quad*8;
  const int tm   = wid >> 2, tn = wid & 3;
  const int am    = tm*16 + ln15;
  const int bn    = tn*16 + ln15;
  const int rbase = tm*16 + quad4;

  unsigned short* const W3T = &MmD[0][0];   // 192*40=7680 ush <= 8192 ush, prologue only

  // ---------------- prologue region 1: static LDS ----------------
  for (int i = tid; i < 192*40; i += 1024){
    int lc = i/40, k = i - lc*40;
    unsigned short v = 0;
    if (k < 12){
      int ch = (lc<64) ? h*64+lc : 448+lc;
      v = f2bf(wsf[OFF_W3 + ch*12 + k]);
    }
    W3T[i] = v;
  }
  for (int i = tid; i < 2*64*28; i += 1024){
    int r = i/28; (&OW[0][0])[r*40 + 12 + (i - r*28)] = 0;
  }
  if (tid < 192){
    int ch = (tid<64) ? h*64+tid : 448+tid;
    float s = conv_b[ch];
    #pragma unroll
    for (int i=0;i<4;i++) s += wsf[OFF_TB + ch*4 + i];
    CBe[tid] = s;
  }
  const float Wd0 = wsf[OFF_WC+(1152+h)*3+0], Wd1 = wsf[OFF_WC+(1152+h)*3+1],
              Wd2 = wsf[OFF_WC+(1152+h)*3+2];
  const float bdt = wsf[OFF_BC + 1152 + h] + dt_bias[h];
  const float A_h = -__expf(A_log[h]);
  const float Dh  = D_param[h];
  for (int cc = wid; cc < 64; cc += 16){
    int t = cc*64 + lane;
    const float* ob = obs + (size_t)t*96 + b*3;
    float draw = bdt + Wd0*ob[0] + Wd1*ob[1] + Wd2*ob[2];
    float dtv = softplusf_(draw);
    float a = A_h * dtv;
    #pragma unroll
    for (int o=1;o<64;o<<=1){
      float u = __shfl_up(a, o);
      if (lane >= o) a += u;
    }
    dt_l[t]  = dtv;
    acs_l[t] = a;
  }

  auto PREFOW = [&](int cn){
    if (tid < 768){
      int tt_ = tid/12, ij = tid - tt_*12;
      int i = ij/3, j = ij - i*3;
      int ts = cn*64 + tt_ - 3 + i;
      OW[cn&1][tt_*40 + ij] = (ts >= 0) ? f2bf(obs[(size_t)ts*96 + b*3 + j])
                                        : (unsigned short)0;
    }
  };
  PREFOW(0);
  PREFOW(1);
  __syncthreads();

  // ---------------- prologue region 2: hoist frags, STAGE(0) ----------------
  short8 afrag1[2], afrag2[2];
  float  cbe1[2][4], cbe2[2];
  #pragma unroll
  for (int e=0;e<2;e++){
    const int idx = wid*2+e;
    const int ct1 = 4 + (idx & 7);
    afrag1[e] = *(const short8*)&W3T[(ct1*16 + ln15)*40 + quad8];
    #pragma unroll
    for (int r=0;r<4;r++) cbe1[e][r] = CBe[ct1*16 + quad4 + r];
    const int ct2 = idx & 7;
    afrag2[e] = *(const short8*)&W3T[(ct2*16 + ln15)*40 + quad8];
    cbe2[e] = CBe[ct2*16 + ln15];
  }

  auto STAGE = [&](int cn, int ps){
    unsigned short* Bp  = &BsT[ps][0];
    unsigned short* Cp  = &CsT[ps][0];
    unsigned short* Xp  = &XDTt[ps][0];
    unsigned short* BDp = &BDTt[ps][0];
    const int tW0 = cn*64;
    const float At_ = acs_l[tW0 + 63];
    #pragma unroll
    for (int e=0;e<2;e++){
      const int idx = wid*2+e;
      const int tt  = idx >> 3;
      const short8 owf = *(const short8*)&OW[cn&1][(tt*16 + ln15)*40 + quad8];
      // ---- o1: ch 64..191 -> Bs / Cs ([t][n] tiles) ----
      {
        const int ct1 = 4 + (idx & 7);
        const int chb = ct1*16 + quad4;
        const int t_  = tt*16 + ln15;
        f32x4 z0 = {0.f,0.f,0.f,0.f};
        f32x4 g = __builtin_amdgcn_mfma_f32_16x16x32_bf16(afrag1[e], owf, z0, 0,0,0);
        float v[4];
        #pragma unroll
        for (int r=0;r<4;r++){
          float pre = g[r] + cbe1[e][r];
          if (cn==0 && tt==0 && ln15 < 3){
            int chg = 448 + chb + r;
            #pragma unroll
            for (int i2=0;i2<3;i2++) if (i2 < 3-ln15) pre -= wsf[OFF_TB + chg*4 + i2];
          }
          v[r] = siluf_(pre);
        }
        if (ct1 < 8){
          *(uint2v*)&Bp[SW(t_, chb-64)]  = (uint2v){cvtpk(v[0],v[1]), cvtpk(v[2],v[3])};
        } else {
          *(uint2v*)&Cp[SW(t_, chb-128)] = (uint2v){cvtpk(v[0],v[1]), cvtpk(v[2],v[3])};
        }
      }
      // ---- o2: ch 0..127 -> XDT / BDT ([p|n][t] tiles) ----
      {
        const int ct2 = idx & 7;
        const int ch2 = ct2*16 + ln15;
        const int tb2 = tt*16 + quad4;
        f32x4 z0 = {0.f,0.f,0.f,0.f};
        f32x4 g = __builtin_amdgcn_mfma_f32_16x16x32_bf16(owf, afrag2[e], z0, 0,0,0);
        float v[4];
        #pragma unroll
        for (int r=0;r<4;r++){
          float pre = g[r] + cbe2[e];
          if (cn==0 && tt==0 && quad==0 && r<3){
            int chg = (ch2<64) ? h*64+ch2 : 448+ch2;
            #pragma unroll
            for (int i2=0;i2<3;i2++) if (i2 < 3-r) pre -= wsf[OFF_TB + chg*4 + i2];
          }
          v[r] = siluf_(pre);
        }
        if (ct2 < 4){
          f32x4 dv = *(const f32x4*)&dt_l[tW0 + tb2];
          *(uint2v*)&Xp[SW(ch2, tb2)] =
            (uint2v){cvtpk(v[0]*dv[0], v[1]*dv[1]), cvtpk(v[2]*dv[2], v[3]*dv[3])};
        } else {
          f32x4 av4 = *(const f32x4*)&acs_l[tW0 + tb2];
          float m0 = v[0]*__expf(At_-av4[0]), m1 = v[1]*__expf(At_-av4[1]);
          float m2 = v[2]*__expf(At_-av4[2]), m3 = v[3]*__expf(At_-av4[3]);
          *(uint2v*)&BDp[SW(ch2-64, tb2)] = (uint2v){cvtpk(m0,m1), cvtpk(m2,m3)};
        }
      }
    }
  };

  auto D_PHASE = [&](int cn, int ps){
    const int tc = cn*64;
    short8 cf[2];
    #pragma unroll
    for (int k=0;k<2;k++) cf[k] = *(const short8*)&CsT[ps][SW(bn, k*32+quad8)];
    f32x4 g2 = {0.f,0.f,0.f,0.f};
    #pragma unroll
    for (int k=0;k<2;k++){
      const short8 av = *(const short8*)&BsT[ps][SW(am, k*32+quad8)];
      g2 = __builtin_amdgcn_mfma_f32_16x16x32_bf16(av, cf[k], g2, 0, 0, 0);
    }
    f32x4 acsS = *(const f32x4*)&acs_l[tc + rbase];
    f32x4 dtS  = *(const f32x4*)&dt_l[tc + rbase];
    float acl  = acs_l[tc + bn];
    float mv[4];
    #pragma unroll
    for (int r=0;r<4;r++){
      int s = rbase + r;
      float m_ = (bn >= s) ? g2[r]*__expf(acl - acsS[r]) : 0.f;
      if (bn == s) m_ += __fdividef(Dh, dtS[r]);
      mv[r] = m_;
    }
    *(uint2v*)&MmD[ps][SW(bn, rbase)] = (uint2v){cvtpk(mv[0],mv[1]), cvtpk(mv[2],mv[3])};
  };

  STAGE(0, 0);
  __syncthreads();

  // ---------------- prologue region 3: D(0), Sb(0)=0 ----------------
  D_PHASE(0, 0);
  *(uint2v*)&SbD[0][SW(bn, rbase)] = (uint2v){0u, 0u};
  __syncthreads();

  f32x4 sreg = {0.f,0.f,0.f,0.f};   // S[n][p]: rows n=rbase+r, col p=bn

  for (int c = 0; c < 64; ++c){
    const int t0 = c*64;
    const int ps = c & 1;

    // ---------- R1: STAGE(c+1), PREFOW(c+2) ----------
    if (c < 63) STAGE(c+1, ps^1);
    if (c < 62) PREFOW(c+2);
    __syncthreads();

    // ---------- R2: E(c) || D(c+1), Sb(c+1) ----------
    {
      short8 mfr[2], ccf[2], xbn[2];
      #pragma unroll
      for (int k=0;k<2;k++){
        int kb = k*32 + quad8;
        mfr[k] = *(const short8*)&MmD[ps][SW(bn, kb)];
        ccf[k] = *(const short8*)&CsT[ps][SW(bn, kb)];
        xbn[k] = *(const short8*)&XDTt[ps][SW(bn, kb)];
      }
      f32x4 y  = {0.f,0.f,0.f,0.f};
      f32x4 yo = {0.f,0.f,0.f,0.f};
      #pragma unroll
      for (int k=0;k<2;k++){
        int kb = k*32 + quad8;
        const short8 xa = *(const short8*)&XDTt[ps][SW(am, kb)];
        y = __builtin_amdgcn_mfma_f32_16x16x32_bf16(xa, mfr[k], y, 0, 0, 0);
      }
      #pragma unroll
      for (int k=0;k<2;k++){
        int kb = k*32 + quad8;
        const short8 sa = *(const short8*)&SbD[ps][SW(am, kb)];
        yo = __builtin_amdgcn_mfma_f32_16x16x32_bf16(sa, ccf[k], yo, 0, 0, 0);
      }
      float eAcl  = __expf(acs_l[t0 + bn]);
      float eAtot = __expf(acs_l[t0 + 63]);
      // Y^T store: thread holds 4 consecutive channels (rbase..+3) at time t0+bn
      uint2v pk = {cvtpk(y[0]+eAcl*yo[0], y[1]+eAcl*yo[1]),
                   cvtpk(y[2]+eAcl*yo[2], y[3]+eAcl*yo[3])};
      *(uint2v*)&Yg[((size_t)(b*4096 + t0 + bn))*512 + h*64 + rbase] = pk;
      #pragma unroll
      for (int r=0;r<4;r++) sreg[r] *= eAtot;
      #pragma unroll
      for (int k=0;k<2;k++){
        int kb = k*32 + quad8;
        const short8 ba = *(const short8*)&BDTt[ps][SW(am, kb)];
        sreg = __builtin_amdgcn_mfma_f32_16x16x32_bf16(ba, xbn[k], sreg, 0, 0, 0);
      }
      if (c < 63){
        D_PHASE(c+1, ps^1);
        *(uint2v*)&SbD[ps^1][SW(bn, rbase)] =
          (uint2v){cvtpk(sreg[0],sreg[1]), cvtpk(sreg[2],sreg[3])};
      }
    }
    __syncthreads();
  }
}

// ---- final: gate with silu(z), RMSNorm, folded out-proj dot, q & logits ----
__global__ __launch_bounds__(256) void final_kernel(
    const unsigned short* __restrict__ Yg, const float* __restrict__ obs,
    const float* __restrict__ wsf, const float* __restrict__ head,
    const float* __restrict__ log_tau, float* __restrict__ out)
{
  int tid = threadIdx.x;
  int wv = tid >> 6, lane = tid & 63;
  // per-thread channels ch = lane*8+u: b128 Yg loads, weights in registers
  float zw0[8], zw1[8], zw2[8], zb[8], znw[8];
  #pragma unroll
  for (int u=0;u<8;u++){
    int ch = lane*8 + u;
    zw0[u] = wsf[OFF_WC + ch*3+0];
    zw1[u] = wsf[OFF_WC + ch*3+1];
    zw2[u] = wsf[OFF_WC + ch*3+2];
    zb[u]  = wsf[OFF_BC + ch];
    znw[u] = wsf[OFF_NW + ch];
  }
  float hsc  = softplusf_(head[0]);
  float itau = __expf(-log_tau[0]);
  int base = blockIdx.x*64 + wv*16;
  for (int rr=0; rr<16; ++rr){
    int row = base + rr;               // b*4096 + t
    int bb = row >> 12, t = row & 4095;
    const float* ob = obs + (size_t)t*96 + bb*3;
    float o0=ob[0], o1=ob[1], o2=ob[2];
    ushort8 yv = *(const ushort8*)&Yg[(size_t)row*512 + lane*8];
    float s2=0.f, sq=0.f;
    #pragma unroll
    for (int u=0;u<8;u++){
      float yf = bf2f(yv[u]);
      float z  = zb[u] + zw0[u]*o0 + zw1[u]*o1 + zw2[u]*o2;
      float yg = yf * siluf_(z);
      s2 = fmaf(yg, yg, s2);
      sq = fmaf(yg, znw[u], sq);
    }
    #pragma unroll
    for (int o=32;o;o>>=1){ s2 += __shfl_xor(s2,o); sq += __shfl_xor(sq,o); }
    if (lane==0){
      float rms = rsqrtf(s2*(1.f/512.f) + 1e-5f);
      float q = sq * rms * hsc;
      out[(size_t)t*32 + bb] = q;
      out[131072 + (size_t)t*32 + bb] = q * itau;
    }
  }
}

extern "C" void kernel_launch(void* const* d_in, const int* in_sizes, int n_in,
                              void* d_out, int out_size, void* d_ws, size_t ws_size,
                              hipStream_t stream) {
  (void)in_sizes; (void)n_in; (void)out_size; (void)ws_size;
  const float* obs        = (const float*)d_in[0];
  const float* W_in       = (const float*)d_in[1];
  const float* b_in       = (const float*)d_in[2];
  const float* in_proj_w  = (const float*)d_in[3];
  const float* conv_w     = (const float*)d_in[4];
  const float* conv_b     = (const float*)d_in[5];
  const float* dt_bias    = (const float*)d_in[6];
  const float* A_log      = (const float*)d_in[7];
  const float* D_param    = (const float*)d_in[8];
  const float* norm_w     = (const float*)d_in[9];
  const float* out_proj_w = (const float*)d_in[10];
  const float* head       = (const float*)d_in[11];
  const float* log_tau    = (const float*)d_in[12];
  float* wsf = (float*)d_ws;
  unsigned short* Yg = (unsigned short*)((char*)d_ws + OFF_Y_BYTES);
  float* out = (float*)d_out;

  prep1_kernel<<<290, 256, 0, stream>>>(in_proj_w, W_in, b_in, wsf);
  prep2_kernel<<<3, 256, 0, stream>>>(conv_w, norm_w, out_proj_w, wsf);
  ssd_kernel<<<256, 1024, 0, stream>>>(obs, conv_b, dt_bias, A_log, D_param, wsf, Yg);
  final_kernel<<<2048, 256, 0, stream>>>(Yg, obs, wsf, head, log_tau, out);
}